// Round 1
// baseline (2748.716 us; speedup 1.0000x reference)
//
#include <hip/hip_runtime.h>

#define HW 65536
#define CDIM 64

typedef __attribute__((ext_vector_type(8))) short bf16x8;
typedef __attribute__((ext_vector_type(4))) float f32x4;
typedef __attribute__((ext_vector_type(4))) unsigned short u16x4;

__device__ __forceinline__ unsigned short f2bf(float x) {
    union { float f; unsigned u; } v; v.f = x;
    unsigned r = v.u + 0x7fffu + ((v.u >> 16) & 1u);
    return (unsigned short)(r >> 16);
}

// ---------------- Pass 1: projections (fp32 accumulate, bf16 out) ----------------

__global__ __launch_bounds__(256, 2)
void proj_qv_kernel(const float* __restrict__ x,
                    const float* __restrict__ wq, const float* __restrict__ bq,
                    const float* __restrict__ wv, const float* __restrict__ bv,
                    unsigned short* __restrict__ qo, unsigned short* __restrict__ vo) {
    const int t = threadIdx.x;
    const int b = blockIdx.y;
    const int pix = blockIdx.x * 256 + t;
    const float* xp = x + (size_t)b * CDIM * HW + pix;

    float aq[CDIM], av[CDIM];
#pragma unroll
    for (int c = 0; c < CDIM; ++c) { aq[c] = bq[c]; av[c] = bv[c]; }

    for (int i = 0; i < CDIM; ++i) {
        float xv = xp[(size_t)i * HW];
#pragma unroll
        for (int c = 0; c < CDIM; ++c) {
            aq[c] = fmaf(wq[c * CDIM + i], xv, aq[c]);
            av[c] = fmaf(wv[c * CDIM + i], xv, av[c]);
        }
    }
    size_t ob = (size_t)b * CDIM * HW + pix;
#pragma unroll
    for (int c = 0; c < CDIM; ++c) {
        qo[ob + (size_t)c * HW] = f2bf(aq[c]);
        vo[ob + (size_t)c * HW] = f2bf(av[c]);
    }
}

__global__ __launch_bounds__(256, 2)
void proj_k_kernel(const float* __restrict__ x,
                   const float* __restrict__ wk, const float* __restrict__ bk,
                   unsigned short* __restrict__ ko) {
    const int t = threadIdx.x;
    const int nb = blockIdx.y;          // (n*B + b), 0..15
    const int pix = blockIdx.x * 256 + t;
    const float* xp = x + (size_t)nb * CDIM * HW + pix;

    float ak[CDIM];
#pragma unroll
    for (int c = 0; c < CDIM; ++c) ak[c] = bk[c];

    for (int i = 0; i < CDIM; ++i) {
        float xv = xp[(size_t)i * HW];
#pragma unroll
        for (int c = 0; c < CDIM; ++c) ak[c] = fmaf(wk[c * CDIM + i], xv, ak[c]);
    }
    size_t ob = (size_t)nb * CDIM * HW + pix;
#pragma unroll
    for (int c = 0; c < CDIM; ++c) ko[ob + (size_t)c * HW] = f2bf(ak[c]);
}

// ---------------- Pass 1.5: 256x256 bf16 transpose (per slice), 64x64 tiles ----------------

__global__ __launch_bounds__(256)
void transpose_kernel(const unsigned short* __restrict__ src, unsigned short* __restrict__ dst) {
    __shared__ unsigned short T[64 * 72];
    const int t = threadIdx.x;
    const int sl = blockIdx.y;
    const int th = blockIdx.x >> 2, tw = blockIdx.x & 3;

    const unsigned short* s = src + (size_t)sl * HW + th * 64 * 256 + tw * 64;
#pragma unroll
    for (int it = 0; it < 2; ++it) {
        int cc = t + it * 256;          // 512 chunks of 8 elems
        int r = cc >> 3, j = cc & 7;
        *(bf16x8*)&T[r * 72 + j * 8] = *(const bf16x8*)&s[r * 256 + j * 8];
    }
    __syncthreads();
    unsigned short* d = dst + (size_t)sl * HW + tw * 64 * 256 + th * 64;
#pragma unroll
    for (int it = 0; it < 2; ++it) {
        int cc = t + it * 256;
        int w = cc >> 3, j = cc & 7;
        bf16x8 val;
#pragma unroll
        for (int e = 0; e < 8; ++e) val[e] = (short)T[(j * 8 + e) * 72 + w];
        *(bf16x8*)&d[w * 256 + j * 8] = val;
    }
}

// ---------------- Pass 2: fused dual attention per (b,c) ----------------
// LDS: P region only — 256 rows x 264 elems bf16 (132 KB). B-operands stream
// directly from global (L1/L2-resident; identical across all 8 waves).
#define PSTRIDE 264

__global__ __launch_bounds__(512, 1)
void attn_kernel(const unsigned short* __restrict__ q,  const unsigned short* __restrict__ qT,
                 const unsigned short* __restrict__ v,  const unsigned short* __restrict__ vT,
                 const unsigned short* __restrict__ k,  const unsigned short* __restrict__ kT,
                 const float* __restrict__ mainx, float* __restrict__ out) {
    __shared__ unsigned short lds[256 * PSTRIDE]; // 135168 bytes

    const int t = threadIdx.x;
    const int wave = t >> 6, lane = t & 63;
    const int quad = lane >> 4, l16 = lane & 15;
    const int bc = blockIdx.x;

    const unsigned short* Q  = q  + (size_t)bc * HW;
    const unsigned short* QT = qT + (size_t)bc * HW;
    const unsigned short* V  = v  + (size_t)bc * HW;
    const unsigned short* VT = vT + (size_t)bc * HW;

    f32x4 oacc[2][16];
#pragma unroll
    for (int rt = 0; rt < 2; ++rt)
#pragma unroll
        for (int ct = 0; ct < 16; ++ct) oacc[rt][ct] = (f32x4){0.f, 0.f, 0.f, 0.f};

    for (int n = 0; n < 4; ++n) {
        const unsigned short* K  = k  + ((size_t)n * 256 + bc) * HW;
        const unsigned short* KT = kT + ((size_t)n * 256 + bc) * HW;

        // P region is re-written this iter; previous space-PV read all rows.
        __syncthreads();

        // ===== TIME attention: S1 = Q K^T, softmax, P1 strip to LDS =====
        for (int rt = 0; rt < 2; ++rt) {
            f32x4 s[16];
#pragma unroll
            for (int ct = 0; ct < 16; ++ct) s[ct] = (f32x4){0.f, 0.f, 0.f, 0.f};
            const unsigned short* arow = Q + (wave * 32 + rt * 16 + l16) * 256 + quad * 8;
            const unsigned short* brow = K + l16 * 256 + quad * 8;
            for (int ks = 0; ks < 8; ++ks) {
                bf16x8 a = *(const bf16x8*)&arow[ks * 32];
#pragma unroll
                for (int ct = 0; ct < 16; ++ct) {
                    bf16x8 bb = *(const bf16x8*)&brow[ct * 16 * 256 + ks * 32];
                    s[ct] = __builtin_amdgcn_mfma_f32_16x16x32_bf16(a, bb, s[ct], 0, 0, 0);
                }
            }
            // row softmax (rows: quad*4+r within strip; 16 lanes of a quad share a row)
#pragma unroll
            for (int r = 0; r < 4; ++r) {
                float m = s[0][r];
#pragma unroll
                for (int ct = 1; ct < 16; ++ct) m = fmaxf(m, s[ct][r]);
#pragma unroll
                for (int off = 1; off < 16; off <<= 1) m = fmaxf(m, __shfl_xor(m, off, 64));
                float sum = 0.f;
#pragma unroll
                for (int ct = 0; ct < 16; ++ct) {
                    float e = __expf((s[ct][r] - m) * 0.0625f);
                    s[ct][r] = e; sum += e;
                }
#pragma unroll
                for (int off = 1; off < 16; off <<= 1) sum += __shfl_xor(sum, off, 64);
                float inv = 1.f / sum;
#pragma unroll
                for (int ct = 0; ct < 16; ++ct) s[ct][r] *= inv;
            }
            // write P1 strip, row-major [h][g] (own wave's rows only)
            int hh = wave * 32 + rt * 16 + quad * 4;
#pragma unroll
            for (int ct = 0; ct < 16; ++ct)
#pragma unroll
                for (int r = 0; r < 4; ++r)
                    lds[(hh + r) * PSTRIDE + ct * 16 + l16] = f2bf(s[ct][r]);
        }
        // PV: out += P1 V  (A = own P1 rows from LDS — same-wave dep, lgkmcnt only;
        //                   B = V^T fragments direct from global, reused across rt)
        for (int gb = 0; gb < 8; ++gb) {
            bf16x8 a0 = *(const bf16x8*)&lds[(wave * 32 + l16) * PSTRIDE + gb * 32 + quad * 8];
            bf16x8 a1 = *(const bf16x8*)&lds[(wave * 32 + 16 + l16) * PSTRIDE + gb * 32 + quad * 8];
#pragma unroll
            for (int ct = 0; ct < 16; ++ct) {
                bf16x8 bb = *(const bf16x8*)&VT[(ct * 16 + l16) * 256 + gb * 32 + quad * 8];
                oacc[0][ct] = __builtin_amdgcn_mfma_f32_16x16x32_bf16(a0, bb, oacc[0][ct], 0, 0, 0);
                oacc[1][ct] = __builtin_amdgcn_mfma_f32_16x16x32_bf16(a1, bb, oacc[1][ct], 0, 0, 0);
            }
        }

        // all waves done reading P1 before P2 (all-row writes) begin
        __syncthreads();

        // ===== SPACE attention: S2 = Q^T K, softmax, P2^T to LDS =====
        for (int rt = 0; rt < 2; ++rt) {
            f32x4 s[16];
#pragma unroll
            for (int ct = 0; ct < 16; ++ct) s[ct] = (f32x4){0.f, 0.f, 0.f, 0.f};
            const unsigned short* arow = QT + (wave * 32 + rt * 16 + l16) * 256 + quad * 8;
            const unsigned short* brow = KT + l16 * 256 + quad * 8;
            for (int ks = 0; ks < 8; ++ks) {
                bf16x8 a = *(const bf16x8*)&arow[ks * 32];
#pragma unroll
                for (int ct = 0; ct < 16; ++ct) {
                    bf16x8 bb = *(const bf16x8*)&brow[ct * 16 * 256 + ks * 32];
                    s[ct] = __builtin_amdgcn_mfma_f32_16x16x32_bf16(a, bb, s[ct], 0, 0, 0);
                }
            }
#pragma unroll
            for (int r = 0; r < 4; ++r) {
                float m = s[0][r];
#pragma unroll
                for (int ct = 1; ct < 16; ++ct) m = fmaxf(m, s[ct][r]);
#pragma unroll
                for (int off = 1; off < 16; off <<= 1) m = fmaxf(m, __shfl_xor(m, off, 64));
                float sum = 0.f;
#pragma unroll
                for (int ct = 0; ct < 16; ++ct) {
                    float e = __expf((s[ct][r] - m) * 0.0625f);
                    s[ct][r] = e; sum += e;
                }
#pragma unroll
                for (int off = 1; off < 16; off <<= 1) sum += __shfl_xor(sum, off, 64);
                float inv = 1.f / sum;
#pragma unroll
                for (int ct = 0; ct < 16; ++ct) s[ct][r] *= inv;
            }
            // write P2 transposed into LDS as [v][w] (w contiguous) — packed 4-elem writes
            int wbase = wave * 32 + rt * 16 + quad * 4;
#pragma unroll
            for (int ct = 0; ct < 16; ++ct) {
                u16x4 pk;
#pragma unroll
                for (int r = 0; r < 4; ++r) pk[r] = f2bf(s[ct][r]);
                *(u16x4*)&lds[(ct * 16 + l16) * PSTRIDE + wbase] = pk;
            }
        }

        // P2 fully written (cross-wave) before space-PV reads
        __syncthreads();

        // PV: out += V P2  (A = V rows direct from global, B = P2^T rows from LDS,
        //                   B reused across rt)
        for (int ks = 0; ks < 8; ++ks) {
            bf16x8 a0 = *(const bf16x8*)&V[(wave * 32 + l16) * 256 + ks * 32 + quad * 8];
            bf16x8 a1 = *(const bf16x8*)&V[(wave * 32 + 16 + l16) * 256 + ks * 32 + quad * 8];
#pragma unroll
            for (int ct = 0; ct < 16; ++ct) {
                bf16x8 bb = *(const bf16x8*)&lds[(ct * 16 + l16) * PSTRIDE + ks * 32 + quad * 8];
                oacc[0][ct] = __builtin_amdgcn_mfma_f32_16x16x32_bf16(a0, bb, oacc[0][ct], 0, 0, 0);
                oacc[1][ct] = __builtin_amdgcn_mfma_f32_16x16x32_bf16(a1, bb, oacc[1][ct], 0, 0, 0);
            }
        }
    }

    // epilogue: out = main + sum
    const float* mp = mainx + (size_t)bc * HW;
    float* op = out + (size_t)bc * HW;
#pragma unroll
    for (int rt = 0; rt < 2; ++rt)
#pragma unroll
        for (int ct = 0; ct < 16; ++ct)
#pragma unroll
            for (int r = 0; r < 4; ++r) {
                int hh = wave * 32 + rt * 16 + quad * 4 + r;
                int ww = ct * 16 + l16;
                op[hh * 256 + ww] = mp[hh * 256 + ww] + oacc[rt][ct][r];
            }
}

// ---------------- launch ----------------

extern "C" void kernel_launch(void* const* d_in, const int* in_sizes, int n_in,
                              void* d_out, int out_size, void* d_ws, size_t ws_size,
                              hipStream_t stream) {
    const float* mainx  = (const float*)d_in[0];
    const float* assist = (const float*)d_in[1];
    const float* wq = (const float*)d_in[2];
    const float* bq = (const float*)d_in[3];
    const float* wk = (const float*)d_in[4];
    const float* bk = (const float*)d_in[5];
    const float* wv = (const float*)d_in[6];
    const float* bv = (const float*)d_in[7];
    float* outp = (float*)d_out;

    unsigned short* ws = (unsigned short*)d_ws;
    const size_t SLICE = (size_t)16777216;          // B*C*H*W elements
    unsigned short* Qw  = ws;
    unsigned short* QTw = ws + SLICE;
    unsigned short* Vw  = ws + 2 * SLICE;
    unsigned short* VTw = ws + 3 * SLICE;
    unsigned short* Kw  = ws + 4 * SLICE;           // N*B*C*H*W = 4*SLICE
    unsigned short* KTw = ws + 8 * SLICE;
    // total: 12 * SLICE * 2 bytes = 402,653,184 bytes

    proj_qv_kernel<<<dim3(256, 4), 256, 0, stream>>>(mainx, wq, bq, wv, bv, Qw, Vw);
    proj_k_kernel<<<dim3(256, 16), 256, 0, stream>>>(assist, wk, bk, Kw);

    transpose_kernel<<<dim3(16, 256), 256, 0, stream>>>(Qw, QTw);
    transpose_kernel<<<dim3(16, 256), 256, 0, stream>>>(Vw, VTw);
    transpose_kernel<<<dim3(16, 1024), 256, 0, stream>>>(Kw, KTw);

    attn_kernel<<<dim3(256), 512, 0, stream>>>(Qw, QTw, Vw, VTw, Kw, KTw, mainx, outp);
}

// Round 2
// 1228.034 us; speedup vs baseline: 2.2383x; 2.2383x over previous
//
#include <hip/hip_runtime.h>

#define HW 65536
#define CDIM 64

typedef __attribute__((ext_vector_type(8))) short bf16x8;
typedef __attribute__((ext_vector_type(4))) float f32x4;
typedef __attribute__((ext_vector_type(4))) unsigned short u16x4;

__device__ __forceinline__ unsigned short f2bf(float x) {
    union { float f; unsigned u; } v; v.f = x;
    unsigned r = v.u + 0x7fffu + ((v.u >> 16) & 1u);
    return (unsigned short)(r >> 16);
}

// ---------------- Pass 1: projections (fp32 accumulate, bf16 out) ----------------

__global__ __launch_bounds__(256, 2)
void proj_qv_kernel(const float* __restrict__ x,
                    const float* __restrict__ wq, const float* __restrict__ bq,
                    const float* __restrict__ wv, const float* __restrict__ bv,
                    unsigned short* __restrict__ qo, unsigned short* __restrict__ vo) {
    const int t = threadIdx.x;
    const int b = blockIdx.y;
    const int pix = blockIdx.x * 256 + t;
    const float* xp = x + (size_t)b * CDIM * HW + pix;

    float aq[CDIM], av[CDIM];
#pragma unroll
    for (int c = 0; c < CDIM; ++c) { aq[c] = bq[c]; av[c] = bv[c]; }

    for (int i = 0; i < CDIM; ++i) {
        float xv = xp[(size_t)i * HW];
#pragma unroll
        for (int c = 0; c < CDIM; ++c) {
            aq[c] = fmaf(wq[c * CDIM + i], xv, aq[c]);
            av[c] = fmaf(wv[c * CDIM + i], xv, av[c]);
        }
    }
    size_t ob = (size_t)b * CDIM * HW + pix;
#pragma unroll
    for (int c = 0; c < CDIM; ++c) {
        qo[ob + (size_t)c * HW] = f2bf(aq[c]);
        vo[ob + (size_t)c * HW] = f2bf(av[c]);
    }
}

__global__ __launch_bounds__(256, 2)
void proj_k_kernel(const float* __restrict__ x,
                   const float* __restrict__ wk, const float* __restrict__ bk,
                   unsigned short* __restrict__ ko) {
    const int t = threadIdx.x;
    const int nb = blockIdx.y;          // (n*B + b), 0..15
    const int pix = blockIdx.x * 256 + t;
    const float* xp = x + (size_t)nb * CDIM * HW + pix;

    float ak[CDIM];
#pragma unroll
    for (int c = 0; c < CDIM; ++c) ak[c] = bk[c];

    for (int i = 0; i < CDIM; ++i) {
        float xv = xp[(size_t)i * HW];
#pragma unroll
        for (int c = 0; c < CDIM; ++c) ak[c] = fmaf(wk[c * CDIM + i], xv, ak[c]);
    }
    size_t ob = (size_t)nb * CDIM * HW + pix;
#pragma unroll
    for (int c = 0; c < CDIM; ++c) ko[ob + (size_t)c * HW] = f2bf(ak[c]);
}

// ---------------- Pass 1.5: 256x256 bf16 transpose (per slice), 64x64 tiles ----------------

__global__ __launch_bounds__(256)
void transpose_kernel(const unsigned short* __restrict__ src, unsigned short* __restrict__ dst) {
    __shared__ unsigned short T[64 * 72];
    const int t = threadIdx.x;
    const int sl = blockIdx.y;
    const int th = blockIdx.x >> 2, tw = blockIdx.x & 3;

    const unsigned short* s = src + (size_t)sl * HW + th * 64 * 256 + tw * 64;
#pragma unroll
    for (int it = 0; it < 2; ++it) {
        int cc = t + it * 256;          // 512 chunks of 8 elems
        int r = cc >> 3, j = cc & 7;
        *(bf16x8*)&T[r * 72 + j * 8] = *(const bf16x8*)&s[r * 256 + j * 8];
    }
    __syncthreads();
    unsigned short* d = dst + (size_t)sl * HW + tw * 64 * 256 + th * 64;
#pragma unroll
    for (int it = 0; it < 2; ++it) {
        int cc = t + it * 256;
        int w = cc >> 3, j = cc & 7;
        bf16x8 val;
#pragma unroll
        for (int e = 0; e < 8; ++e) val[e] = (short)T[(j * 8 + e) * 72 + w];
        *(bf16x8*)&d[w * 256 + j * 8] = val;
    }
}

// ---------------- Pass 2: PS kernel — PS1 = sum_n softmax(Q K_n^T), PS2T = (sum_n softmax(Q^T K_n))^T
// One block = 128 output rows (strip) of one (bc, flavor). psum accumulates the
// softmaxed P over n in registers; single bf16 write at the end.
// LDS: one 256-row x 32-col staged B tile, stride 40 (20 KB) -> 4+ blocks/CU.

#define KSTR 40

__global__ __launch_bounds__(512, 4)
void ps_kernel(const unsigned short* __restrict__ q, const unsigned short* __restrict__ qT,
               const unsigned short* __restrict__ kk,
               unsigned short* __restrict__ ps1, unsigned short* __restrict__ ps2t) {
    __shared__ unsigned short TB[256 * KSTR];
    const int t = threadIdx.x;
    const int wave = t >> 6, lane = t & 63;
    const int quad = lane >> 4, l16 = lane & 15;
    const int bx = blockIdx.x;
    const int bc = bx & 255;            // same-bc blocks are 256 apart -> same XCD, all co-resident
    const int strip = (bx >> 8) & 1;
    const int flavor = bx >> 9;         // 0 = time (Q,K), 1 = space (QT, K^T via LDS transpose)

    const unsigned short* A = (flavor ? qT : q) + (size_t)bc * HW;
    const int rowA = strip * 128 + wave * 16 + l16;

    // A-fragments are n-invariant: hoist all 8 k-blocks once.
    bf16x8 areg[8];
#pragma unroll
    for (int ks = 0; ks < 8; ++ks)
        areg[ks] = *(const bf16x8*)&A[rowA * 256 + ks * 32 + quad * 8];

    f32x4 psum[16];
#pragma unroll
    for (int ct = 0; ct < 16; ++ct) psum[ct] = (f32x4){0.f, 0.f, 0.f, 0.f};

    for (int n = 0; n < 4; ++n) {
        const unsigned short* Ksl = kk + ((size_t)(n * 256 + bc)) * HW;
        f32x4 s_[16];
#pragma unroll
        for (int ct = 0; ct < 16; ++ct) s_[ct] = (f32x4){0.f, 0.f, 0.f, 0.f};

        for (int ks = 0; ks < 8; ++ks) {
            __syncthreads();
            if (flavor == 0) {
                // stage B[g][k=w-block]: rows g of K, cols ks*32..+32 (b128 writes, 2-way free)
#pragma unroll
                for (int it = 0; it < 2; ++it) {
                    int cc = t + it * 512;
                    int r = cc >> 2, j = cc & 3;
                    *(bf16x8*)&TB[r * KSTR + j * 8] =
                        *(const bf16x8*)&Ksl[r * 256 + ks * 32 + j * 8];
                }
            } else {
                // transposed stage B[v][k=h-block]: read 32 h-rows of K coalesced,
                // scatter u16 into [v][h_l] (4-way conflict, correctness-safe)
#pragma unroll
                for (int it = 0; it < 2; ++it) {
                    int cc = t + it * 512;
                    int h_l = cc & 31, vc = cc >> 5;
                    bf16x8 d = *(const bf16x8*)&Ksl[(ks * 32 + h_l) * 256 + vc * 8];
#pragma unroll
                    for (int e = 0; e < 8; ++e)
                        TB[(vc * 8 + e) * KSTR + h_l] = (unsigned short)d[e];
                }
            }
            __syncthreads();
            bf16x8 a = areg[ks];
#pragma unroll
            for (int ct = 0; ct < 16; ++ct) {
                bf16x8 bb = *(const bf16x8*)&TB[(ct * 16 + l16) * KSTR + quad * 8];
                s_[ct] = __builtin_amdgcn_mfma_f32_16x16x32_bf16(a, bb, s_[ct], 0, 0, 0);
            }
        }
        // row softmax (row = quad*4+r within wave strip; 16 l16 lanes share a row),
        // then accumulate normalized P into psum.
#pragma unroll
        for (int r = 0; r < 4; ++r) {
            float m = s_[0][r];
#pragma unroll
            for (int ct = 1; ct < 16; ++ct) m = fmaxf(m, s_[ct][r]);
#pragma unroll
            for (int off = 1; off < 16; off <<= 1) m = fmaxf(m, __shfl_xor(m, off, 64));
            float sum = 0.f;
#pragma unroll
            for (int ct = 0; ct < 16; ++ct) {
                float e = __expf((s_[ct][r] - m) * 0.0625f);
                s_[ct][r] = e; sum += e;
            }
#pragma unroll
            for (int off = 1; off < 16; off <<= 1) sum += __shfl_xor(sum, off, 64);
            float inv = 1.f / sum;
#pragma unroll
            for (int ct = 0; ct < 16; ++ct) psum[ct][r] += s_[ct][r] * inv;
        }
    }

    if (flavor == 0) {
        // PS1[bc][h][g] row-major
        unsigned short* o = ps1 + (size_t)bc * HW;
        int hh = strip * 128 + wave * 16 + quad * 4;
#pragma unroll
        for (int ct = 0; ct < 16; ++ct)
#pragma unroll
            for (int r = 0; r < 4; ++r)
                o[(hh + r) * 256 + ct * 16 + l16] = f2bf(psum[ct][r]);
    } else {
        // PS2T[bc][v][w] — transposed scatter, u16x4 packed (8B aligned)
        unsigned short* o = ps2t + (size_t)bc * HW;
        int wbase = strip * 128 + wave * 16 + quad * 4;
#pragma unroll
        for (int ct = 0; ct < 16; ++ct) {
            u16x4 pk;
#pragma unroll
            for (int r = 0; r < 4; ++r) pk[r] = f2bf(psum[ct][r]);
            *(u16x4*)&o[(ct * 16 + l16) * 256 + wbase] = pk;
        }
    }
}

// ---------------- Pass 3: out = main + PS1*V + V*PS2 (two 256^3 GEMMs per bc) ----------------

__global__ __launch_bounds__(512, 4)
void final_kernel(const unsigned short* __restrict__ ps1, const unsigned short* __restrict__ ps2t,
                  const unsigned short* __restrict__ v, const unsigned short* __restrict__ vT,
                  const float* __restrict__ mainx, float* __restrict__ out) {
    __shared__ unsigned short TB[256 * KSTR];
    const int t = threadIdx.x;
    const int wave = t >> 6, lane = t & 63;
    const int quad = lane >> 4, l16 = lane & 15;
    const int bx = blockIdx.x;
    const int bc = bx & 255, strip = bx >> 8;

    const int rowA = strip * 128 + wave * 16 + l16;

    f32x4 oacc[16];
#pragma unroll
    for (int ct = 0; ct < 16; ++ct) oacc[ct] = (f32x4){0.f, 0.f, 0.f, 0.f};

    // GEMM1: out[h,w] += sum_g PS1[h,g] * V[g,w]   (A = PS1 rows, B = VT rows w, g-contig)
    {
        const unsigned short* Ap = ps1 + (size_t)bc * HW;
        const unsigned short* Bp = vT + (size_t)bc * HW;
        bf16x8 areg[8];
#pragma unroll
        for (int gb = 0; gb < 8; ++gb)
            areg[gb] = *(const bf16x8*)&Ap[rowA * 256 + gb * 32 + quad * 8];
        for (int gb = 0; gb < 8; ++gb) {
            __syncthreads();
#pragma unroll
            for (int it = 0; it < 2; ++it) {
                int cc = t + it * 512;
                int r = cc >> 2, j = cc & 3;
                *(bf16x8*)&TB[r * KSTR + j * 8] =
                    *(const bf16x8*)&Bp[r * 256 + gb * 32 + j * 8];
            }
            __syncthreads();
#pragma unroll
            for (int ct = 0; ct < 16; ++ct) {
                bf16x8 bb = *(const bf16x8*)&TB[(ct * 16 + l16) * KSTR + quad * 8];
                oacc[ct] = __builtin_amdgcn_mfma_f32_16x16x32_bf16(areg[gb], bb, oacc[ct], 0, 0, 0);
            }
        }
    }
    // GEMM2: out[h,v] += sum_w V[h,w] * PS2[w,v]   (A = V rows, B = PS2T rows v, w-contig)
    {
        const unsigned short* Ap = v + (size_t)bc * HW;
        const unsigned short* Bp = ps2t + (size_t)bc * HW;
        bf16x8 areg[8];
#pragma unroll
        for (int ks = 0; ks < 8; ++ks)
            areg[ks] = *(const bf16x8*)&Ap[rowA * 256 + ks * 32 + quad * 8];
        for (int ks = 0; ks < 8; ++ks) {
            __syncthreads();
#pragma unroll
            for (int it = 0; it < 2; ++it) {
                int cc = t + it * 512;
                int r = cc >> 2, j = cc & 3;
                *(bf16x8*)&TB[r * KSTR + j * 8] =
                    *(const bf16x8*)&Bp[r * 256 + ks * 32 + j * 8];
            }
            __syncthreads();
#pragma unroll
            for (int ct = 0; ct < 16; ++ct) {
                bf16x8 bb = *(const bf16x8*)&TB[(ct * 16 + l16) * KSTR + quad * 8];
                oacc[ct] = __builtin_amdgcn_mfma_f32_16x16x32_bf16(areg[ks], bb, oacc[ct], 0, 0, 0);
            }
        }
    }

    // epilogue: out = main + acc
    const float* mp = mainx + (size_t)bc * HW;
    float* op = out + (size_t)bc * HW;
#pragma unroll
    for (int ct = 0; ct < 16; ++ct)
#pragma unroll
        for (int r = 0; r < 4; ++r) {
            int hh = strip * 128 + wave * 16 + quad * 4 + r;
            int ww = ct * 16 + l16;
            op[hh * 256 + ww] = mp[hh * 256 + ww] + oacc[ct][r];
        }
}

// ---------------- launch ----------------

extern "C" void kernel_launch(void* const* d_in, const int* in_sizes, int n_in,
                              void* d_out, int out_size, void* d_ws, size_t ws_size,
                              hipStream_t stream) {
    const float* mainx  = (const float*)d_in[0];
    const float* assist = (const float*)d_in[1];
    const float* wq = (const float*)d_in[2];
    const float* bq = (const float*)d_in[3];
    const float* wk = (const float*)d_in[4];
    const float* bk = (const float*)d_in[5];
    const float* wv = (const float*)d_in[6];
    const float* bv = (const float*)d_in[7];
    float* outp = (float*)d_out;

    unsigned short* ws = (unsigned short*)d_ws;
    const size_t SLICE = (size_t)16777216;          // B*C*H*W elements
    unsigned short* Qw   = ws;
    unsigned short* QTw  = ws + SLICE;
    unsigned short* Vw   = ws + 2 * SLICE;
    unsigned short* VTw  = ws + 3 * SLICE;
    unsigned short* PS1w = ws + 4 * SLICE;
    unsigned short* PS2Tw= ws + 5 * SLICE;
    unsigned short* Kw   = ws + 6 * SLICE;          // N*B*C*H*W = 4*SLICE
    // total: 10 * SLICE * 2 bytes = 335,544,320 bytes

    proj_qv_kernel<<<dim3(256, 4), 256, 0, stream>>>(mainx, wq, bq, wv, bv, Qw, Vw);
    proj_k_kernel<<<dim3(256, 16), 256, 0, stream>>>(assist, wk, bk, Kw);

    transpose_kernel<<<dim3(16, 256), 256, 0, stream>>>(Qw, QTw);
    transpose_kernel<<<dim3(16, 256), 256, 0, stream>>>(Vw, VTw);

    ps_kernel<<<dim3(1024), 512, 0, stream>>>(Qw, QTw, Kw, PS1w, PS2Tw);
    final_kernel<<<dim3(512), 512, 0, stream>>>(PS1w, PS2Tw, Vw, VTw, mainx, outp);
}